// Round 5
// baseline (56.468 us; speedup 1.0000x reference)
//
#include <hip/hip_runtime.h>

#define B_   4
#define CIN  64
#define COUT 64
#define H_   128
#define W_   128
#define HW   (H_*W_)
#define KK   9
#define PIX  (B_*H_*W_)    // 65536
#define BTILE 64           // pixels per block (4 waves x 16)
#define NBLK (PIX / BTILE) // 1024

typedef short bf16x8 __attribute__((ext_vector_type(8)));
typedef float f32x4  __attribute__((ext_vector_type(4)));
typedef float f32x2  __attribute__((ext_vector_type(2)));
typedef int   i32x4  __attribute__((ext_vector_type(4)));
typedef unsigned int u32;
typedef unsigned int u32x4 __attribute__((ext_vector_type(4)));

__device__ __forceinline__ unsigned short f2bf(float f) {
    unsigned int u = __float_as_uint(f);
    u = (u + 0x7FFFu + ((u >> 16) & 1u)) >> 16;
    return (unsigned short)u;
}

// ---- Kernel 1: x (B,CIN,H,W) f32 -> xt (B,H,W,CIN) bf16 (channels-last) ----
__global__ __launch_bounds__(256) void k_transpose(const float* __restrict__ x,
                                                   unsigned short* __restrict__ xt) {
    __shared__ float lds[64 * 129];
    int bi = blockIdx.x;            // b*H + i
    int b = bi >> 7, i = bi & 127;
    int tid = threadIdx.x;
#pragma unroll
    for (int cc = 0; cc < 32; ++cc) {
        int c = cc * 2 + (tid >> 7);
        int w = tid & 127;
        lds[c * 129 + w] = x[((b * CIN + c) * H_ + i) * W_ + w];
    }
    __syncthreads();
#pragma unroll
    for (int q = 0; q < 32; ++q) {
        int c = tid & 63;
        int w = q * 4 + (tid >> 6);
        xt[((b * H_ + i) * W_ + w) * CIN + c] = f2bf(lds[c * 129 + w]);
    }
}

// ---- Kernel 2: weight (COUT,CIN,3,3) f32 -> B-fragment-ordered bf16 ----
// wtf[s][nt][lane][j] = W[n][c][kpos];  kg = s*32 + (lane>>4)*8 + j = kpos*64 + c
__global__ __launch_bounds__(256) void k_weight(const float* __restrict__ w,
                                                unsigned short* __restrict__ wtf) {
    int t = blockIdx.x * 256 + threadIdx.x;
    if (t >= 18 * 4 * 64 * 8) return;
    int j    = t & 7;
    int lane = (t >> 3) & 63;
    int nt   = (t >> 9) & 3;
    int s    = t >> 11;
    int kg   = s * 32 + ((lane >> 4) << 3) + j;
    int n    = nt * 16 + (lane & 15);
    int kpos = kg >> 6, c = kg & 63;
    wtf[t] = f2bf(w[(n * CIN + c) * 9 + kpos]);
}

struct Meta { i32x4 a; f32x4 w; };

// ---- Main: per-wave 16-pixel GEMM, registered meta, 3-deep SW pipeline ----
__global__ __launch_bounds__(256, 3) void k_main(
    const unsigned short* __restrict__ xt,
    const float* __restrict__ offset,
    const float* __restrict__ mask,
    const unsigned short* __restrict__ wtf,
    const float* __restrict__ bias,
    float* __restrict__ out) {
    __shared__ __align__(16) float cst[COUT * 68];   // C staging only, 17.4 KB

    const int tid  = threadIdx.x;
    const int lane = tid & 63;
    const int wv   = tid >> 6;
    // XCD-aware swizzle: 1024 blocks, 8 XCDs -> XCD x owns contiguous 128-tile chunk
    const int tile = ((blockIdx.x & 7) << 7) + (blockIdx.x >> 3);
    const int g0   = tile * BTILE;
    const int b  = g0 >> 14;
    const int i  = (g0 >> 7) & 127;
    const int j0 = g0 & 127;
    const int p  = lane & 15;              // this lane's pixel within wave tile
    const int j  = j0 + wv * 16 + p;
    const int cof = (lane >> 4) << 4;      // channel-group byte offset

    const float* offp = offset + (size_t)b * 18 * HW + i * W_ + j;
    const float* mskp = mask   + (size_t)b * 9  * HW + i * W_ + j;
    const char*  xb   = (const char*)xt + (size_t)b * (HW * CIN * 2);
    const bf16x8* wp  = (const bf16x8*)wtf;

    float oi[3], oj[3], om[3];
    Meta  mt[3];
    u32x4 G[2][4];
    bf16x8 Bf[2][4];
    f32x4 acc0 = {0,0,0,0}, acc1 = {0,0,0,0}, acc2 = {0,0,0,0}, acc3 = {0,0,0,0};

#define LOAD_OFF(kp, sl) do { \
    oi[sl] = offp[(2*(kp))*HW]; \
    oj[sl] = offp[(2*(kp)+1)*HW]; \
    om[sl] = mskp[(kp)*HW]; } while(0)

#define CALC_META(kp, sl) do { \
    float ci = oi[sl] + (float)(i + (kp)/3 - 1); \
    float cj = oj[sl] + (float)(j + (kp)%3 - 1); \
    float msk = om[sl]; \
    float fli = floorf(ci), flj = floorf(cj); \
    float fi = ci - fli, fj = cj - flj; \
    int li = (int)fli, lj = (int)flj; \
    int li1 = li + 1, lj1 = lj + 1; \
    float vy0 = (li  >= 0 && li  < H_) ? 1.f : 0.f; \
    float vy1 = (li1 >= 0 && li1 < H_) ? 1.f : 0.f; \
    float vx0 = (lj  >= 0 && lj  < W_) ? 1.f : 0.f; \
    float vx1 = (lj1 >= 0 && lj1 < W_) ? 1.f : 0.f; \
    int y0 = min(max(li,  0), H_-1), y1 = min(max(li1, 0), H_-1); \
    int x0 = min(max(lj,  0), W_-1), x1 = min(max(lj1, 0), W_-1); \
    float gi = fi * msk, gj = fj * msk; \
    float w11 = gi * fj; \
    mt[sl].w.x = (msk - gi - gj + w11) * vy0 * vx0; \
    mt[sl].w.y = (gj - w11) * vy0 * vx1; \
    mt[sl].w.z = (gi - w11) * vy1 * vx0; \
    mt[sl].w.w = w11 * vy1 * vx1; \
    mt[sl].a.x = (y0 * W_ + x0) * (CIN*2); \
    mt[sl].a.y = (y0 * W_ + x1) * (CIN*2); \
    mt[sl].a.z = (y1 * W_ + x0) * (CIN*2); \
    mt[sl].a.w = (y1 * W_ + x1) * (CIN*2); } while(0)

#define ISSUE_G(s, gs) do { \
    const Meta& m = mt[((s)>>1) % 3]; \
    int c = cof + ((s)&1) * 64; \
    G[gs][0] = *(const u32x4*)(xb + m.a.x + c); \
    G[gs][1] = *(const u32x4*)(xb + m.a.y + c); \
    G[gs][2] = *(const u32x4*)(xb + m.a.z + c); \
    G[gs][3] = *(const u32x4*)(xb + m.a.w + c); } while(0)

#define ISSUE_B(s, gs) do { \
    Bf[gs][0] = wp[((s)*4+0)*64 + lane]; \
    Bf[gs][1] = wp[((s)*4+1)*64 + lane]; \
    Bf[gs][2] = wp[((s)*4+2)*64 + lane]; \
    Bf[gs][3] = wp[((s)*4+3)*64 + lane]; } while(0)

#define BLEND_MFMA(s, gs) do { \
    const f32x4 w4 = mt[((s)>>1) % 3].w; \
    f32x2 wx = {w4.x, w4.x}, wy = {w4.y, w4.y}; \
    f32x2 wz = {w4.z, w4.z}, ww = {w4.w, w4.w}; \
    u32x4 po; \
    _Pragma("unroll") \
    for (int q = 0; q < 4; ++q) { \
        f32x2 c00 = {__uint_as_float(G[gs][0][q] << 16), __uint_as_float(G[gs][0][q] & 0xFFFF0000u)}; \
        f32x2 c01 = {__uint_as_float(G[gs][1][q] << 16), __uint_as_float(G[gs][1][q] & 0xFFFF0000u)}; \
        f32x2 c10 = {__uint_as_float(G[gs][2][q] << 16), __uint_as_float(G[gs][2][q] & 0xFFFF0000u)}; \
        f32x2 c11 = {__uint_as_float(G[gs][3][q] << 16), __uint_as_float(G[gs][3][q] & 0xFFFF0000u)}; \
        f32x2 r = wx * c00 + wy * c01 + wz * c10 + ww * c11; \
        po[q] = __builtin_amdgcn_perm(__float_as_uint(r.y) + 0x8000u, \
                                      __float_as_uint(r.x) + 0x8000u, 0x07060302u); \
    } \
    bf16x8 af; *(u32x4*)&af = po; \
    acc0 = __builtin_amdgcn_mfma_f32_16x16x32_bf16(af, Bf[gs][0], acc0, 0, 0, 0); \
    acc1 = __builtin_amdgcn_mfma_f32_16x16x32_bf16(af, Bf[gs][1], acc1, 0, 0, 0); \
    acc2 = __builtin_amdgcn_mfma_f32_16x16x32_bf16(af, Bf[gs][2], acc2, 0, 0, 0); \
    acc3 = __builtin_amdgcn_mfma_f32_16x16x32_bf16(af, Bf[gs][3], acc3, 0, 0, 0); } while(0)

    // ---- prologue: fill the pipeline ----
    LOAD_OFF(0, 0); LOAD_OFF(1, 1); LOAD_OFF(2, 2);
    CALC_META(0, 0); CALC_META(1, 1);
    ISSUE_G(0, 0); ISSUE_B(0, 0);

    // ---- steady state: per s-body (s = kp*2 + h):
    //   issue G/B for s+1 (meta ready 1 body ahead)
    //   h==0: issue off-loads kp+3;  h==1: compute meta kp+2
    //   blend + 4 MFMA on s (gathers issued 1 body ago)
#pragma unroll
    for (int s = 0; s < 18; ++s) {
        const int kp = s >> 1, h = s & 1;
        if (s + 1 < 18) { ISSUE_G(s + 1, (s + 1) & 1); ISSUE_B(s + 1, (s + 1) & 1); }
        if (h == 0 && kp + 3 <= 8) LOAD_OFF(kp + 3, (kp + 3) % 3);
        if (h == 1 && kp + 2 <= 8) CALC_META(kp + 2, (kp + 2) % 3);
        BLEND_MFMA(s, s & 1);
    }

    // ---- epilogue: stage C in LDS (pad 68), coalesced nontemporal write ----
    {
        f32x4 v0 = acc0, v1 = acc1, v2 = acc2, v3 = acc3;
        float bs0 = bias[p], bs1 = bias[16 + p], bs2 = bias[32 + p], bs3 = bias[48 + p];
#pragma unroll
        for (int r = 0; r < 4; ++r) { v0[r] += bs0; v1[r] += bs1; v2[r] += bs2; v3[r] += bs3; }
        const int pm = wv * 16 + ((lane >> 4) << 2);
        *(f32x4*)&cst[(p)      * 68 + pm] = v0;
        *(f32x4*)&cst[(16 + p) * 68 + pm] = v1;
        *(f32x4*)&cst[(32 + p) * 68 + pm] = v2;
        *(f32x4*)&cst[(48 + p) * 68 + pm] = v3;
    }
    __syncthreads();
    const int cl = tid >> 4;             // 0..15
    const int px = (tid & 15) * 4;       // 0..60
    const size_t obase = (size_t)b * (COUT * HW) + i * W_ + j0;
#pragma unroll
    for (int c4 = 0; c4 < 4; ++c4) {
        int cout = c4 * 16 + cl;
        f32x4 vv = *(const f32x4*)&cst[cout * 68 + px];
        __builtin_nontemporal_store(vv, (f32x4*)&out[obase + (size_t)cout * HW + px]);
    }
}

extern "C" void kernel_launch(void* const* d_in, const int* in_sizes, int n_in,
                              void* d_out, int out_size, void* d_ws, size_t ws_size,
                              hipStream_t stream) {
    const float* x      = (const float*)d_in[0];
    const float* offset = (const float*)d_in[1];
    const float* mask   = (const float*)d_in[2];
    const float* weight = (const float*)d_in[3];
    const float* bias   = (const float*)d_in[4];
    float* out = (float*)d_out;
    unsigned short* xt  = (unsigned short*)d_ws;
    unsigned short* wtf = xt + (size_t)B_ * H_ * W_ * CIN;   // +8 MB

    k_transpose<<<B_ * H_, 256, 0, stream>>>(x, xt);
    k_weight<<<144, 256, 0, stream>>>(weight, wtf);
    k_main<<<NBLK, 256, 0, stream>>>(xt, offset, mask, wtf, bias, out);
}

// Round 6
// 43.275 us; speedup vs baseline: 1.3049x; 1.3049x over previous
//
#include <hip/hip_runtime.h>

#define B_   4
#define CIN  64
#define COUT 64
#define H_   128
#define W_   128
#define HW   (H_*W_)
#define KK   9
#define PIX  (B_*H_*W_)
#define R_   4             // halo
#define REG  16            // staged region is 16x16 records
#define NBLK 1024          // 4 b x 16 ti x 16 tj

typedef short bf16x8 __attribute__((ext_vector_type(8)));
typedef float f32x4  __attribute__((ext_vector_type(4)));
typedef float f32x2  __attribute__((ext_vector_type(2)));
typedef unsigned int u32;
typedef unsigned int u32x4 __attribute__((ext_vector_type(4)));

__device__ __forceinline__ unsigned short f2bf(float f) {
    unsigned int u = __float_as_uint(f);
    u = (u + 0x7FFFu + ((u >> 16) & 1u)) >> 16;
    return (unsigned short)u;
}

// ---- Kernel 1: x (B,CIN,H,W) f32 -> xt (B,H,W,CIN) bf16 (channels-last) ----
__global__ __launch_bounds__(256) void k_transpose(const float* __restrict__ x,
                                                   unsigned short* __restrict__ xt) {
    __shared__ float lds[64 * 129];
    int bi = blockIdx.x;            // b*H + i
    int b = bi >> 7, i = bi & 127;
    int tid = threadIdx.x;
#pragma unroll
    for (int cc = 0; cc < 32; ++cc) {
        int c = cc * 2 + (tid >> 7);
        int w = tid & 127;
        lds[c * 129 + w] = x[((b * CIN + c) * H_ + i) * W_ + w];
    }
    __syncthreads();
#pragma unroll
    for (int q = 0; q < 32; ++q) {
        int c = tid & 63;
        int w = q * 4 + (tid >> 6);
        xt[((b * H_ + i) * W_ + w) * CIN + c] = f2bf(lds[c * 129 + w]);
    }
}

// ---- Kernel 2: weight (COUT,CIN,3,3) f32 -> B-fragment-ordered bf16 ----
// wtf[s][nt][lane][j] = W[n][c][kpos];  kg = s*32 + (lane>>4)*8 + j = kpos*64 + c
__global__ __launch_bounds__(256) void k_weight(const float* __restrict__ w,
                                                unsigned short* __restrict__ wtf) {
    int t = blockIdx.x * 256 + threadIdx.x;
    if (t >= 18 * 4 * 64 * 8) return;
    int j    = t & 7;
    int lane = (t >> 3) & 63;
    int nt   = (t >> 9) & 3;
    int s    = t >> 11;
    int kg   = s * 32 + ((lane >> 4) << 3) + j;
    int n    = nt * 16 + (lane & 15);
    int kpos = kg >> 6, c = kg & 63;
    wtf[t] = f2bf(w[(n * CIN + c) * 9 + kpos]);
}

// ---- Main: LDS spatial tile -> bilinear from LDS -> MFMA GEMM ----
// Block = 8x8 pixel tile, 4 waves; wave wv owns rows (2wv, 2wv+1) = 16 px.
__global__ __launch_bounds__(256, 4) void k_main(
    const unsigned short* __restrict__ xt,
    const float* __restrict__ offset,
    const float* __restrict__ mask,
    const unsigned short* __restrict__ wtf,
    const float* __restrict__ bias,
    float* __restrict__ out) {
    __shared__ __align__(16) unsigned char smem[REG * REG * 128];  // 32 KB

    const int tid  = threadIdx.x;
    const int lane = tid & 63;
    const int wv   = tid >> 6;
    // XCD swizzle (1024 % 8 == 0): each XCD gets contiguous 128 tiles
    const int T  = ((blockIdx.x & 7) << 7) + (blockIdx.x >> 3);
    const int b  = T >> 8;
    const int i0 = ((T >> 4) & 15) * 8;
    const int j0 = (T & 15) * 8;
    const char* xb = (const char*)xt + (size_t)b * HW * 128;

    // -------- stage 16x16 record region (halo R_=4), chunk-rotation swizzle ----
    {
        const int iA = i0 - R_, jA = j0 - R_;
#pragma unroll
        for (int k = 0; k < 8; ++k) {
            int linear = k * 256 + tid;
            int rec = linear >> 3, c = linear & 7;
            int gr = min(max(iA + (rec >> 4), 0), H_ - 1);
            int gc = min(max(jA + (rec & 15), 0), W_ - 1);
            u32x4 v = *(const u32x4*)(xb + ((gr * W_ + gc) << 7) + (c << 4));
            *(u32x4*)(smem + (rec << 7) + (((c + rec) & 7) << 4)) = v;
        }
    }
    __syncthreads();

    // -------- main loop --------
    const int p  = lane & 15;           // px within wave (row=p>>3, col=p&7)
    const int g  = lane >> 4;           // channel group
    const int ir = i0 + wv * 2 + (p >> 3);   // global pixel row
    const int jc = j0 + (p & 7);             // global pixel col
    const float* offp = offset + (size_t)b * 18 * HW + ir * W_ + jc;
    const float* mskp = mask   + (size_t)b * 9  * HW + ir * W_ + jc;
    const bf16x8* wp  = (const bf16x8*)wtf;

    f32x4 acc0 = {0,0,0,0}, acc1 = {0,0,0,0}, acc2 = {0,0,0,0}, acc3 = {0,0,0,0};

#pragma unroll
    for (int kp = 0; kp < 9; ++kp) {
        float oi  = offp[(2 * kp) * HW];
        float oj  = offp[(2 * kp + 1) * HW];
        float msk = mskp[kp * HW];
        float ci = oi + (float)(ir + kp / 3 - 1);
        float cj = oj + (float)(jc + kp % 3 - 1);
        float fli = floorf(ci), flj = floorf(cj);
        float fi = ci - fli, fj = cj - flj;
        int li = (int)fli, lj = (int)flj;
        int li1 = li + 1, lj1 = lj + 1;
        float vy0 = (li  >= 0 && li  < H_) ? 1.f : 0.f;
        float vy1 = (li1 >= 0 && li1 < H_) ? 1.f : 0.f;
        float vx0 = (lj  >= 0 && lj  < W_) ? 1.f : 0.f;
        float vx1 = (lj1 >= 0 && lj1 < W_) ? 1.f : 0.f;
        float gi = fi * msk, gj = fj * msk;
        float w11 = gi * fj;
        f32x4 w4;
        w4.x = (msk - gi - gj + w11) * vy0 * vx0;
        w4.y = (gj - w11) * vy0 * vx1;
        w4.z = (gi - w11) * vy1 * vx0;
        w4.w = w11 * vy1 * vx1;
        // global fallback byte addrs (clamped)
        int y0 = min(max(li,  0), H_ - 1), y1 = min(max(li1, 0), H_ - 1);
        int x0 = min(max(lj,  0), W_ - 1), x1 = min(max(lj1, 0), W_ - 1);
        int a00 = (y0 * W_ + x0) << 7, a01 = (y0 * W_ + x1) << 7;
        int a10 = (y1 * W_ + x0) << 7, a11 = (y1 * W_ + x1) << 7;
        // in-region test (unclamped): need li,li+1 and lj,lj+1 within 16-row box
        int rli = li - (i0 - R_), rlj = lj - (j0 - R_);
        bool inr = ((unsigned)rli <= 14u) && ((unsigned)rlj <= 14u);
        int rli_c = min(max(rli, 0), 14), rlj_c = min(max(rlj, 0), 14);
        int r00 = rli_c * 16 + rlj_c;
        int r01 = r00 + 1, r10 = r00 + 16, r11 = r00 + 17;

#pragma unroll
        for (int h = 0; h < 2; ++h) {
            int ch = h * 4 + g;
            u32x4 q00 = *(const u32x4*)(smem + (r00 << 7) + (((ch + r00) & 7) << 4));
            u32x4 q01 = *(const u32x4*)(smem + (r01 << 7) + (((ch + r01) & 7) << 4));
            u32x4 q10 = *(const u32x4*)(smem + (r10 << 7) + (((ch + r10) & 7) << 4));
            u32x4 q11 = *(const u32x4*)(smem + (r11 << 7) + (((ch + r11) & 7) << 4));
            if (!inr) {   // rare exec-masked fallback, clamped global addrs
                int c = (g << 4) + (h << 6);
                q00 = *(const u32x4*)(xb + a00 + c);
                q01 = *(const u32x4*)(xb + a01 + c);
                q10 = *(const u32x4*)(xb + a10 + c);
                q11 = *(const u32x4*)(xb + a11 + c);
            }
            f32x2 wx = {w4.x, w4.x}, wy = {w4.y, w4.y};
            f32x2 wz = {w4.z, w4.z}, ww = {w4.w, w4.w};
            u32x4 po;
#pragma unroll
            for (int q = 0; q < 4; ++q) {
                f32x2 c00 = {__uint_as_float(q00[q] << 16), __uint_as_float(q00[q] & 0xFFFF0000u)};
                f32x2 c01 = {__uint_as_float(q01[q] << 16), __uint_as_float(q01[q] & 0xFFFF0000u)};
                f32x2 c10 = {__uint_as_float(q10[q] << 16), __uint_as_float(q10[q] & 0xFFFF0000u)};
                f32x2 c11 = {__uint_as_float(q11[q] << 16), __uint_as_float(q11[q] & 0xFFFF0000u)};
                f32x2 r = wx * c00 + wy * c01 + wz * c10 + ww * c11;
                po[q] = __builtin_amdgcn_perm(__float_as_uint(r.y) + 0x8000u,
                                              __float_as_uint(r.x) + 0x8000u, 0x07060302u);
            }
            bf16x8 af; *(u32x4*)&af = po;
            int s = kp * 2 + h;
            acc0 = __builtin_amdgcn_mfma_f32_16x16x32_bf16(af, wp[(s*4+0)*64 + lane], acc0, 0, 0, 0);
            acc1 = __builtin_amdgcn_mfma_f32_16x16x32_bf16(af, wp[(s*4+1)*64 + lane], acc1, 0, 0, 0);
            acc2 = __builtin_amdgcn_mfma_f32_16x16x32_bf16(af, wp[(s*4+2)*64 + lane], acc2, 0, 0, 0);
            acc3 = __builtin_amdgcn_mfma_f32_16x16x32_bf16(af, wp[(s*4+3)*64 + lane], acc3, 0, 0, 0);
        }
    }

    // -------- epilogue: reuse smem as cst[64][68] f32, coalesced writes ------
    __syncthreads();
    float* cst = (float*)smem;
    {
        f32x4 v0 = acc0, v1 = acc1, v2 = acc2, v3 = acc3;
        float bs0 = bias[p], bs1 = bias[16 + p], bs2 = bias[32 + p], bs3 = bias[48 + p];
#pragma unroll
        for (int r = 0; r < 4; ++r) { v0[r] += bs0; v1[r] += bs1; v2[r] += bs2; v3[r] += bs3; }
        const int pm = wv * 16 + (g << 2);   // px_local base for this lane's 4 m-rows
        *(f32x4*)&cst[(p)      * 68 + pm] = v0;
        *(f32x4*)&cst[(16 + p) * 68 + pm] = v1;
        *(f32x4*)&cst[(32 + p) * 68 + pm] = v2;
        *(f32x4*)&cst[(48 + p) * 68 + pm] = v3;
    }
    __syncthreads();
    const int cl  = tid >> 4;            // 0..15
    const int px4 = (tid & 15) * 4;      // local px 0..60 (row=px4>>3, col=px4&7)
    const size_t obase = (size_t)b * (COUT * HW) + (i0 + (px4 >> 3)) * W_ + j0 + (px4 & 7);
#pragma unroll
    for (int c4 = 0; c4 < 4; ++c4) {
        int cout = c4 * 16 + cl;
        f32x4 vv = *(const f32x4*)&cst[cout * 68 + px4];
        __builtin_nontemporal_store(vv, (f32x4*)&out[obase + (size_t)cout * HW]);
    }
}

extern "C" void kernel_launch(void* const* d_in, const int* in_sizes, int n_in,
                              void* d_out, int out_size, void* d_ws, size_t ws_size,
                              hipStream_t stream) {
    const float* x      = (const float*)d_in[0];
    const float* offset = (const float*)d_in[1];
    const float* mask   = (const float*)d_in[2];
    const float* weight = (const float*)d_in[3];
    const float* bias   = (const float*)d_in[4];
    float* out = (float*)d_out;
    unsigned short* xt  = (unsigned short*)d_ws;
    unsigned short* wtf = xt + (size_t)B_ * H_ * W_ * CIN;   // +8 MB

    k_transpose<<<B_ * H_, 256, 0, stream>>>(x, xt);
    k_weight<<<144, 256, 0, stream>>>(weight, wtf);
    k_main<<<NBLK, 256, 0, stream>>>(xt, offset, mask, wtf, bias, out);
}

// Round 7
// 37.977 us; speedup vs baseline: 1.4869x; 1.1395x over previous
//
#include <hip/hip_runtime.h>

#define B_   4
#define CIN  64
#define COUT 64
#define H_   128
#define W_   128
#define HW   (H_*W_)
#define KK   9
#define ROWS_R 16          // staged region rows (8 + 2*4 halo)
#define COLS_R 24          // staged region cols (16 + 2*4 halo)
#define OFFB  (ROWS_R * COLS_R * 128)   // 49152: offset/mask LDS base
#define SMEMB (OFFB + 27 * 128 * 4)     // 62976 total
#define NBLK 512           // 4 b x 16 ti x 8 tj

typedef short bf16x8 __attribute__((ext_vector_type(8)));
typedef float f32x4  __attribute__((ext_vector_type(4)));
typedef float f32x2  __attribute__((ext_vector_type(2)));
typedef unsigned int u32;
typedef unsigned int u32x4 __attribute__((ext_vector_type(4)));

__device__ __forceinline__ unsigned short f2bf(float f) {
    unsigned int u = __float_as_uint(f);
    u = (u + 0x7FFFu + ((u >> 16) & 1u)) >> 16;
    return (unsigned short)u;
}

// ---- Kernel 1: x (B,CIN,H,W) f32 -> xt (B,H,W,CIN) bf16 (channels-last) ----
__global__ __launch_bounds__(256) void k_transpose(const float* __restrict__ x,
                                                   unsigned short* __restrict__ xt) {
    __shared__ float lds[64 * 129];
    int bi = blockIdx.x;            // b*H + i
    int b = bi >> 7, i = bi & 127;
    int tid = threadIdx.x;
#pragma unroll
    for (int cc = 0; cc < 32; ++cc) {
        int c = cc * 2 + (tid >> 7);
        int w = tid & 127;
        lds[c * 129 + w] = x[((b * CIN + c) * H_ + i) * W_ + w];
    }
    __syncthreads();
#pragma unroll
    for (int q = 0; q < 32; ++q) {
        int c = tid & 63;
        int w = q * 4 + (tid >> 6);
        xt[((b * H_ + i) * W_ + w) * CIN + c] = f2bf(lds[c * 129 + w]);
    }
}

// ---- Kernel 2: weight (COUT,CIN,3,3) f32 -> B-fragment-ordered bf16 ----
// wtf[s][nt][lane][j] = W[n][c][kpos];  kg = s*32 + (lane>>4)*8 + j = kpos*64 + c
__global__ __launch_bounds__(256) void k_weight(const float* __restrict__ w,
                                                unsigned short* __restrict__ wtf) {
    int t = blockIdx.x * 256 + threadIdx.x;
    if (t >= 18 * 4 * 64 * 8) return;
    int j    = t & 7;
    int lane = (t >> 3) & 63;
    int nt   = (t >> 9) & 3;
    int s    = t >> 11;
    int kg   = s * 32 + ((lane >> 4) << 3) + j;
    int n    = nt * 16 + (lane & 15);
    int kpos = kg >> 6, c = kg & 63;
    wtf[t] = f2bf(w[(n * CIN + c) * 9 + kpos]);
}

// ---- Main: 8x16 px tile, 8 waves (wave = row), LDS tile + LDS offsets ----
__global__ __launch_bounds__(512, 4) void k_main(
    const unsigned short* __restrict__ xt,
    const float* __restrict__ offset,
    const float* __restrict__ mask,
    const unsigned short* __restrict__ wtf,
    const float* __restrict__ bias,
    float* __restrict__ out) {
    __shared__ __align__(16) unsigned char smem[SMEMB];   // 61.5 KB

    const int tid  = threadIdx.x;
    const int lane = tid & 63;
    const int wv   = tid >> 6;          // 0..7 = pixel row within tile
    // XCD swizzle (512 % 8 == 0): each XCD gets 64 contiguous tiles
    const int T  = ((blockIdx.x & 7) << 6) + (blockIdx.x >> 3);
    const int b  = T >> 7;
    const int i0 = ((T >> 3) & 15) * 8;
    const int j0 = (T & 7) * 16;
    const char* xb = (const char*)xt + (size_t)b * HW * 128;

    // -------- stage 16x24 record region (halo 4), chunk-rotation swizzle ----
    {
        const int iA = i0 - 4, jA = j0 - 4;
#pragma unroll
        for (int k = 0; k < 6; ++k) {
            int idx = k * 512 + tid;          // chunk index, 3072 total
            int rec = idx >> 3, c = idx & 7;
            int rr = rec / COLS_R, cc = rec - rr * COLS_R;
            int gr = min(max(iA + rr, 0), H_ - 1);
            int gc = min(max(jA + cc, 0), W_ - 1);
            u32x4 v = *(const u32x4*)(xb + (((gr << 7) + gc) << 7) + (c << 4));
            *(u32x4*)(smem + (rec << 7) + (((c + rec) & 7) << 4)) = v;
        }
    }
    // -------- stage offset+mask planes [27][8][16] f32 --------
    {
        const float* op = offset + (size_t)b * 18 * HW;
        const float* mp = mask   + (size_t)b * 9  * HW;
#pragma unroll
        for (int k = 0; k < 2; ++k) {
            int idx = k * 512 + tid;          // 864 f32x4 chunks
            if (idx < 864) {
                int q = idx >> 5, rem = idx & 31;
                int row = rem >> 2, c4 = (rem & 3) << 2;
                const float* src = (q < 18 ? op + q * HW : mp + (q - 18) * HW)
                                   + (i0 + row) * W_ + j0 + c4;
                *(f32x4*)(smem + OFFB + idx * 16) = *(const f32x4*)src;
            }
        }
    }
    __syncthreads();

    // -------- per-wave: preload this row's 27 offset/mask values ----------
    const int p  = lane & 15;            // px col within row
    const int g  = lane >> 4;            // channel group
    const int ir = i0 + wv;
    const int jc = j0 + p;
    const float* offl = (const float*)(smem + OFFB);
    float offv[18], mskv[9];
#pragma unroll
    for (int q = 0; q < 18; ++q) offv[q] = offl[q * 128 + wv * 16 + p];
#pragma unroll
    for (int q = 0; q < 9; ++q)  mskv[q] = offl[(18 + q) * 128 + wv * 16 + p];

    const bf16x8* wp = (const bf16x8*)wtf;
    f32x4 acc0 = {0,0,0,0}, acc1 = {0,0,0,0}, acc2 = {0,0,0,0}, acc3 = {0,0,0,0};

#pragma unroll
    for (int kp = 0; kp < 9; ++kp) {
        float oi  = offv[2 * kp];
        float oj  = offv[2 * kp + 1];
        float msk = mskv[kp];
        float ci = oi + (float)(ir + kp / 3 - 1);
        float cj = oj + (float)(jc + kp % 3 - 1);
        float fli = floorf(ci), flj = floorf(cj);
        float fi = ci - fli, fj = cj - flj;
        int li = (int)fli, lj = (int)flj;
        int li1 = li + 1, lj1 = lj + 1;
        float vy0 = (li  >= 0 && li  < H_) ? 1.f : 0.f;
        float vy1 = (li1 >= 0 && li1 < H_) ? 1.f : 0.f;
        float vx0 = (lj  >= 0 && lj  < W_) ? 1.f : 0.f;
        float vx1 = (lj1 >= 0 && lj1 < W_) ? 1.f : 0.f;
        float gi = fi * msk, gj = fj * msk;
        float w11 = gi * fj;
        f32x4 w4;
        w4.x = (msk - gi - gj + w11) * vy0 * vx0;
        w4.y = (gj - w11) * vy0 * vx1;
        w4.z = (gi - w11) * vy1 * vx0;
        w4.w = w11 * vy1 * vx1;
        // global fallback byte addrs (clamped)
        int y0 = min(max(li,  0), H_ - 1), y1 = min(max(li1, 0), H_ - 1);
        int x0 = min(max(lj,  0), W_ - 1), x1 = min(max(lj1, 0), W_ - 1);
        int a00 = ((y0 << 7) + x0) << 7, a01 = ((y0 << 7) + x1) << 7;
        int a10 = ((y1 << 7) + x0) << 7, a11 = ((y1 << 7) + x1) << 7;
        // in-region test (unclamped)
        int rli = li - (i0 - 4), rlj = lj - (j0 - 4);
        bool inr = ((unsigned)rli <= (unsigned)(ROWS_R - 2)) &&
                   ((unsigned)rlj <= (unsigned)(COLS_R - 2));
        int rli_c = min(max(rli, 0), ROWS_R - 2), rlj_c = min(max(rlj, 0), COLS_R - 2);
        int r00 = rli_c * COLS_R + rlj_c;
        int r01 = r00 + 1, r10 = r00 + COLS_R, r11 = r00 + COLS_R + 1;

#pragma unroll
        for (int h = 0; h < 2; ++h) {
            int ch = h * 4 + g;
            u32x4 q00 = *(const u32x4*)(smem + (r00 << 7) + (((ch + r00) & 7) << 4));
            u32x4 q01 = *(const u32x4*)(smem + (r01 << 7) + (((ch + r01) & 7) << 4));
            u32x4 q10 = *(const u32x4*)(smem + (r10 << 7) + (((ch + r10) & 7) << 4));
            u32x4 q11 = *(const u32x4*)(smem + (r11 << 7) + (((ch + r11) & 7) << 4));
            if (!inr) {   // rare exec-masked fallback
                int c = (g << 4) + (h << 6);
                q00 = *(const u32x4*)(xb + a00 + c);
                q01 = *(const u32x4*)(xb + a01 + c);
                q10 = *(const u32x4*)(xb + a10 + c);
                q11 = *(const u32x4*)(xb + a11 + c);
            }
            f32x2 wx = {w4.x, w4.x}, wy = {w4.y, w4.y};
            f32x2 wz = {w4.z, w4.z}, ww = {w4.w, w4.w};
            u32x4 po;
#pragma unroll
            for (int q = 0; q < 4; ++q) {
                f32x2 c00 = {__uint_as_float(q00[q] << 16), __uint_as_float(q00[q] & 0xFFFF0000u)};
                f32x2 c01 = {__uint_as_float(q01[q] << 16), __uint_as_float(q01[q] & 0xFFFF0000u)};
                f32x2 c10 = {__uint_as_float(q10[q] << 16), __uint_as_float(q10[q] & 0xFFFF0000u)};
                f32x2 c11 = {__uint_as_float(q11[q] << 16), __uint_as_float(q11[q] & 0xFFFF0000u)};
                f32x2 r = wx * c00 + wy * c01 + wz * c10 + ww * c11;
                po[q] = __builtin_amdgcn_perm(__float_as_uint(r.y) + 0x8000u,
                                              __float_as_uint(r.x) + 0x8000u, 0x07060302u);
            }
            bf16x8 af; *(u32x4*)&af = po;
            int s = kp * 2 + h;
            acc0 = __builtin_amdgcn_mfma_f32_16x16x32_bf16(af, wp[(s*4+0)*64 + lane], acc0, 0, 0, 0);
            acc1 = __builtin_amdgcn_mfma_f32_16x16x32_bf16(af, wp[(s*4+1)*64 + lane], acc1, 0, 0, 0);
            acc2 = __builtin_amdgcn_mfma_f32_16x16x32_bf16(af, wp[(s*4+2)*64 + lane], acc2, 0, 0, 0);
            acc3 = __builtin_amdgcn_mfma_f32_16x16x32_bf16(af, wp[(s*4+3)*64 + lane], acc3, 0, 0, 0);
        }
    }

    // -------- epilogue: reuse smem as cst[64][132] f32, full-line writes ----
    __syncthreads();
    float* cst = (float*)smem;
    {
        f32x4 v0 = acc0, v1 = acc1, v2 = acc2, v3 = acc3;
        float bs0 = bias[p], bs1 = bias[16 + p], bs2 = bias[32 + p], bs3 = bias[48 + p];
#pragma unroll
        for (int r = 0; r < 4; ++r) { v0[r] += bs0; v1[r] += bs1; v2[r] += bs2; v3[r] += bs3; }
        const int pm = wv * 16 + (g << 2);   // pixel-local base for lane's 4 m-rows
        *(f32x4*)&cst[(p)      * 132 + pm] = v0;
        *(f32x4*)&cst[(16 + p) * 132 + pm] = v1;
        *(f32x4*)&cst[(32 + p) * 132 + pm] = v2;
        *(f32x4*)&cst[(48 + p) * 132 + pm] = v3;
    }
    __syncthreads();
    const size_t obase = (size_t)b * (COUT * HW) + i0 * W_ + j0;
#pragma unroll
    for (int k = 0; k < 4; ++k) {
        int idx = k * 512 + tid;            // 2048 f32x4 chunks
        int cout = idx >> 5, chunk = idx & 31;
        int row = chunk >> 2, col = (chunk & 3) << 2;
        f32x4 vv = *(const f32x4*)&cst[cout * 132 + chunk * 4];
        __builtin_nontemporal_store(vv,
            (f32x4*)&out[obase + (size_t)cout * HW + row * W_ + col]);
    }
}

extern "C" void kernel_launch(void* const* d_in, const int* in_sizes, int n_in,
                              void* d_out, int out_size, void* d_ws, size_t ws_size,
                              hipStream_t stream) {
    const float* x      = (const float*)d_in[0];
    const float* offset = (const float*)d_in[1];
    const float* mask   = (const float*)d_in[2];
    const float* weight = (const float*)d_in[3];
    const float* bias   = (const float*)d_in[4];
    float* out = (float*)d_out;
    unsigned short* xt  = (unsigned short*)d_ws;
    unsigned short* wtf = xt + (size_t)B_ * H_ * W_ * CIN;   // +8 MB

    k_transpose<<<B_ * H_, 256, 0, stream>>>(x, xt);
    k_weight<<<144, 256, 0, stream>>>(weight, wtf);
    k_main<<<NBLK, 512, 0, stream>>>(xt, offset, mask, wtf, bias, out);
}

// Round 8
// 35.566 us; speedup vs baseline: 1.5877x; 1.0678x over previous
//
#include <hip/hip_runtime.h>

#define B_   4
#define CIN  64
#define COUT 64
#define H_   128
#define W_   128
#define HW   (H_*W_)
#define KK   9
#define HALO 3
#define ROWS_R (8 + 2*HALO)    // 14
#define COLS_R (16 + 2*HALO)   // 22
#define RECS   (ROWS_R * COLS_R)        // 308
#define OFFB   (RECS * 128)             // 39424: offset/mask LDS base
#define SMEMB  (OFFB + 27 * 128 * 4)    // 53248 total -> 3 blocks/CU
#define NBLK 512           // 4 b x 16 ti x 8 tj

typedef short bf16x8 __attribute__((ext_vector_type(8)));
typedef float f32x4  __attribute__((ext_vector_type(4)));
typedef float f32x2  __attribute__((ext_vector_type(2)));
typedef unsigned int u32;
typedef unsigned int u32x4 __attribute__((ext_vector_type(4)));

__device__ __forceinline__ unsigned short f2bf(float f) {
    unsigned int u = __float_as_uint(f);
    u = (u + 0x7FFFu + ((u >> 16) & 1u)) >> 16;
    return (unsigned short)u;
}

// ---- Kernel 1: x (B,CIN,H,W) f32 -> xt (B,H,W,CIN) bf16 (channels-last) ----
__global__ __launch_bounds__(256) void k_transpose(const float* __restrict__ x,
                                                   unsigned short* __restrict__ xt) {
    __shared__ float lds[64 * 129];
    int bi = blockIdx.x;            // b*H + i
    int b = bi >> 7, i = bi & 127;
    int tid = threadIdx.x;
#pragma unroll
    for (int cc = 0; cc < 32; ++cc) {
        int c = cc * 2 + (tid >> 7);
        int w = tid & 127;
        lds[c * 129 + w] = x[((b * CIN + c) * H_ + i) * W_ + w];
    }
    __syncthreads();
#pragma unroll
    for (int q = 0; q < 32; ++q) {
        int c = tid & 63;
        int w = q * 4 + (tid >> 6);
        xt[((b * H_ + i) * W_ + w) * CIN + c] = f2bf(lds[c * 129 + w]);
    }
}

// ---- Kernel 2: weight (COUT,CIN,3,3) f32 -> B-fragment-ordered bf16 ----
// wtf[s][nt][lane][j] = W[n][c][kpos];  kg = s*32 + (lane>>4)*8 + j = kpos*64 + c
__global__ __launch_bounds__(256) void k_weight(const float* __restrict__ w,
                                                unsigned short* __restrict__ wtf) {
    int t = blockIdx.x * 256 + threadIdx.x;
    if (t >= 18 * 4 * 64 * 8) return;
    int j    = t & 7;
    int lane = (t >> 3) & 63;
    int nt   = (t >> 9) & 3;
    int s    = t >> 11;
    int kg   = s * 32 + ((lane >> 4) << 3) + j;
    int n    = nt * 16 + (lane & 15);
    int kpos = kg >> 6, c = kg & 63;
    wtf[t] = f2bf(w[(n * CIN + c) * 9 + kpos]);
}

// ---- Main: 8x16 px tile, 8 waves (wave = row), LDS tile + LDS offsets ----
__global__ __launch_bounds__(512, 6) void k_main(
    const unsigned short* __restrict__ xt,
    const float* __restrict__ offset,
    const float* __restrict__ mask,
    const unsigned short* __restrict__ wtf,
    const float* __restrict__ bias,
    float* __restrict__ out) {
    __shared__ __align__(16) unsigned char smem[SMEMB];   // 52 KB

    const int tid  = threadIdx.x;
    const int lane = tid & 63;
    const int wv   = tid >> 6;          // 0..7 = pixel row within tile
    // XCD swizzle (512 % 8 == 0): each XCD gets 64 contiguous tiles
    const int T  = ((blockIdx.x & 7) << 6) + (blockIdx.x >> 3);
    const int b  = T >> 7;
    const int i0 = ((T >> 3) & 15) * 8;
    const int j0 = (T & 7) * 16;
    const char* xb = (const char*)xt + (size_t)b * HW * 128;

    // -------- stage 14x22 record region (halo 3), chunk-rotation swizzle ----
    {
        const int iA = i0 - HALO, jA = j0 - HALO;
#pragma unroll
        for (int k = 0; k < 5; ++k) {
            int idx = k * 512 + tid;          // chunk index, 2464 total
            if (idx < RECS * 8) {
                int rec = idx >> 3, c = idx & 7;
                int rr = rec / COLS_R, cc = rec - rr * COLS_R;
                int gr = min(max(iA + rr, 0), H_ - 1);
                int gc = min(max(jA + cc, 0), W_ - 1);
                u32x4 v = *(const u32x4*)(xb + (((gr << 7) + gc) << 7) + (c << 4));
                *(u32x4*)(smem + (rec << 7) + (((c + rec) & 7) << 4)) = v;
            }
        }
    }
    // -------- stage offset+mask planes [27][8][16] f32 --------
    {
        const float* op = offset + (size_t)b * 18 * HW;
        const float* mp = mask   + (size_t)b * 9  * HW;
#pragma unroll
        for (int k = 0; k < 2; ++k) {
            int idx = k * 512 + tid;          // 864 f32x4 chunks
            if (idx < 864) {
                int q = idx >> 5, rem = idx & 31;
                int row = rem >> 2, c4 = (rem & 3) << 2;
                const float* src = (q < 18 ? op + q * HW : mp + (q - 18) * HW)
                                   + (i0 + row) * W_ + j0 + c4;
                *(f32x4*)(smem + OFFB + idx * 16) = *(const f32x4*)src;
            }
        }
    }
    __syncthreads();

    const int p  = lane & 15;            // px col within row
    const int g  = lane >> 4;            // channel group
    const int ir = i0 + wv;
    const int jc = j0 + p;
    const float* offl = (const float*)(smem + OFFB) + wv * 16 + p;
    const bf16x8* wp = (const bf16x8*)wtf;
    f32x4 acc0 = {0,0,0,0}, acc1 = {0,0,0,0}, acc2 = {0,0,0,0}, acc3 = {0,0,0,0};

#pragma unroll
    for (int kp = 0; kp < 9; ++kp) {
        float oi  = offl[(2 * kp) * 128];
        float oj  = offl[(2 * kp + 1) * 128];
        float msk = offl[(18 + kp) * 128];
        float ci = oi + (float)(ir + kp / 3 - 1);
        float cj = oj + (float)(jc + kp % 3 - 1);
        float fli = floorf(ci), flj = floorf(cj);
        float fi = ci - fli, fj = cj - flj;
        int li = (int)fli, lj = (int)flj;
        int li1 = li + 1, lj1 = lj + 1;
        float vy0 = (li  >= 0 && li  < H_) ? 1.f : 0.f;
        float vy1 = (li1 >= 0 && li1 < H_) ? 1.f : 0.f;
        float vx0 = (lj  >= 0 && lj  < W_) ? 1.f : 0.f;
        float vx1 = (lj1 >= 0 && lj1 < W_) ? 1.f : 0.f;
        float gi = fi * msk, gj = fj * msk;
        float w11 = gi * fj;
        f32x4 w4;
        w4.x = (msk - gi - gj + w11) * vy0 * vx0;
        w4.y = (gj - w11) * vy0 * vx1;
        w4.z = (gi - w11) * vy1 * vx0;
        w4.w = w11 * vy1 * vx1;
        // global fallback byte addrs (clamped)
        int y0 = min(max(li,  0), H_ - 1), y1 = min(max(li1, 0), H_ - 1);
        int x0 = min(max(lj,  0), W_ - 1), x1 = min(max(lj1, 0), W_ - 1);
        int a00 = ((y0 << 7) + x0) << 7, a01 = ((y0 << 7) + x1) << 7;
        int a10 = ((y1 << 7) + x0) << 7, a11 = ((y1 << 7) + x1) << 7;
        // in-region test (unclamped)
        int rli = li - (i0 - HALO), rlj = lj - (j0 - HALO);
        bool inr = ((unsigned)rli <= (unsigned)(ROWS_R - 2)) &&
                   ((unsigned)rlj <= (unsigned)(COLS_R - 2));
        int rli_c = min(max(rli, 0), ROWS_R - 2), rlj_c = min(max(rlj, 0), COLS_R - 2);
        int r00 = rli_c * COLS_R + rlj_c;
        int r01 = r00 + 1, r10 = r00 + COLS_R, r11 = r00 + COLS_R + 1;

        // issue all 8 corner reads (both k-halves) before blending
        u32x4 q00[2], q01[2], q10[2], q11[2];
#pragma unroll
        for (int h = 0; h < 2; ++h) {
            int ch = h * 4 + g;
            q00[h] = *(const u32x4*)(smem + (r00 << 7) + (((ch + r00) & 7) << 4));
            q01[h] = *(const u32x4*)(smem + (r01 << 7) + (((ch + r01) & 7) << 4));
            q10[h] = *(const u32x4*)(smem + (r10 << 7) + (((ch + r10) & 7) << 4));
            q11[h] = *(const u32x4*)(smem + (r11 << 7) + (((ch + r11) & 7) << 4));
        }
        if (!inr) {   // rare exec-masked fallback
#pragma unroll
            for (int h = 0; h < 2; ++h) {
                int c = (g << 4) + (h << 6);
                q00[h] = *(const u32x4*)(xb + a00 + c);
                q01[h] = *(const u32x4*)(xb + a01 + c);
                q10[h] = *(const u32x4*)(xb + a10 + c);
                q11[h] = *(const u32x4*)(xb + a11 + c);
            }
        }
        f32x2 wx = {w4.x, w4.x}, wy = {w4.y, w4.y};
        f32x2 wz = {w4.z, w4.z}, ww = {w4.w, w4.w};
#pragma unroll
        for (int h = 0; h < 2; ++h) {
            u32x4 po;
#pragma unroll
            for (int q = 0; q < 4; ++q) {
                f32x2 c00 = {__uint_as_float(q00[h][q] << 16), __uint_as_float(q00[h][q] & 0xFFFF0000u)};
                f32x2 c01 = {__uint_as_float(q01[h][q] << 16), __uint_as_float(q01[h][q] & 0xFFFF0000u)};
                f32x2 c10 = {__uint_as_float(q10[h][q] << 16), __uint_as_float(q10[h][q] & 0xFFFF0000u)};
                f32x2 c11 = {__uint_as_float(q11[h][q] << 16), __uint_as_float(q11[h][q] & 0xFFFF0000u)};
                f32x2 r = wx * c00 + wy * c01 + wz * c10 + ww * c11;
                po[q] = __builtin_amdgcn_perm(__float_as_uint(r.y) + 0x8000u,
                                              __float_as_uint(r.x) + 0x8000u, 0x07060302u);
            }
            bf16x8 af; *(u32x4*)&af = po;
            int s = kp * 2 + h;
            acc0 = __builtin_amdgcn_mfma_f32_16x16x32_bf16(af, wp[(s*4+0)*64 + lane], acc0, 0, 0, 0);
            acc1 = __builtin_amdgcn_mfma_f32_16x16x32_bf16(af, wp[(s*4+1)*64 + lane], acc1, 0, 0, 0);
            acc2 = __builtin_amdgcn_mfma_f32_16x16x32_bf16(af, wp[(s*4+2)*64 + lane], acc2, 0, 0, 0);
            acc3 = __builtin_amdgcn_mfma_f32_16x16x32_bf16(af, wp[(s*4+3)*64 + lane], acc3, 0, 0, 0);
        }
    }

    // -------- epilogue: reuse smem as cst[64][132] f32, full-line writes ----
    __syncthreads();
    float* cst = (float*)smem;
    {
        f32x4 v0 = acc0, v1 = acc1, v2 = acc2, v3 = acc3;
        float bs0 = bias[p], bs1 = bias[16 + p], bs2 = bias[32 + p], bs3 = bias[48 + p];
#pragma unroll
        for (int r = 0; r < 4; ++r) { v0[r] += bs0; v1[r] += bs1; v2[r] += bs2; v3[r] += bs3; }
        const int pm = wv * 16 + (g << 2);   // pixel-local base for lane's 4 m-rows
        *(f32x4*)&cst[(p)      * 132 + pm] = v0;
        *(f32x4*)&cst[(16 + p) * 132 + pm] = v1;
        *(f32x4*)&cst[(32 + p) * 132 + pm] = v2;
        *(f32x4*)&cst[(48 + p) * 132 + pm] = v3;
    }
    __syncthreads();
    const size_t obase = (size_t)b * (COUT * HW) + i0 * W_ + j0;
#pragma unroll
    for (int k = 0; k < 4; ++k) {
        int idx = k * 512 + tid;            // 2048 f32x4 chunks
        int cout = idx >> 5, chunk = idx & 31;
        int row = chunk >> 2, col = (chunk & 3) << 2;
        f32x4 vv = *(const f32x4*)&cst[cout * 132 + chunk * 4];
        __builtin_nontemporal_store(vv,
            (f32x4*)&out[obase + (size_t)cout * HW + row * W_ + col]);
    }
}

extern "C" void kernel_launch(void* const* d_in, const int* in_sizes, int n_in,
                              void* d_out, int out_size, void* d_ws, size_t ws_size,
                              hipStream_t stream) {
    const float* x      = (const float*)d_in[0];
    const float* offset = (const float*)d_in[1];
    const float* mask   = (const float*)d_in[2];
    const float* weight = (const float*)d_in[3];
    const float* bias   = (const float*)d_in[4];
    float* out = (float*)d_out;
    unsigned short* xt  = (unsigned short*)d_ws;
    unsigned short* wtf = xt + (size_t)B_ * H_ * W_ * CIN;   // +8 MB

    k_transpose<<<B_ * H_, 256, 0, stream>>>(x, xt);
    k_weight<<<144, 256, 0, stream>>>(weight, wtf);
    k_main<<<NBLK, 512, 0, stream>>>(xt, offset, mask, wtf, bias, out);
}